// Round 3
// baseline (347.282 us; speedup 1.0000x reference)
//
#include <hip/hip_runtime.h>
#include <hip/hip_bf16.h>

typedef __attribute__((ext_vector_type(4))) float f32x4;
typedef __attribute__((ext_vector_type(8))) short bf16x8;

// global -> LDS direct DMA, 16 B/lane. LDS dest = wave-uniform base + lane*16.
#define GLDS16(gp, lp) __builtin_amdgcn_global_load_lds( \
    (__attribute__((address_space(1))) void*)(void*)(gp), \
    (__attribute__((address_space(3))) void*)(lp), 16, 0, 0)

static constexpr int Mtot = 4 * 24 * 512;   // 49152 rows (b,h,n)
static constexpr int Ktot = 768;            // k = f*128 + i  (feature-major!)
static constexpr int Otot = 512;
static constexpr int Hh   = 24;

__device__ inline unsigned short f2bf(float f) {
    __hip_bfloat16 h = __float2bfloat16(f);
    unsigned short u;
    __builtin_memcpy(&u, &h, 2);
    return u;
}

// Pack [base_w | spline_w] -> bf16 Wt[O][768], k = f*128 + i.
// tid = o*192 + f*32 + c4 ; thread writes 4 bf16 = one uint2 at index tid.
__global__ __launch_bounds__(256) void prep_W(
        const float* __restrict__ bw, const float* __restrict__ sw,
        uint2* __restrict__ Wt)
{
    int tid = blockIdx.x * 256 + threadIdx.x;   // 512*6*32 = 98304
    int c4 = tid & 31;
    int f  = (tid >> 5) % 6;
    int o  = tid / 192;
    int i  = c4 * 4;
    float v[4];
    if (f == 0) {
        float4 t = *(const float4*)(bw + o * 128 + i);
        v[0] = t.x; v[1] = t.y; v[2] = t.z; v[3] = t.w;
    } else {
        const float* sp = sw + (long)(o * 128 + i) * 5 + (f - 1);
        v[0] = sp[0]; v[1] = sp[5]; v[2] = sp[10]; v[3] = sp[15];
    }
    uint2 w;
    w.x = f2bf(v[0]) | ((unsigned)f2bf(v[1]) << 16);
    w.y = f2bf(v[2]) | ((unsigned)f2bf(v[3]) << 16);
    Wt[tid] = w;
}

// Fused: generate A-tile (silu/RBF features of x,t_emb) in-kernel -> LDS,
// stage W via global_load_lds, MFMA. Block tile 128x256, 4 waves 2x2,
// wave tile 64x128, BK=64, XOR chunk swizzle on both LDS tiles.
__global__ __launch_bounds__(256, 2) void gemm_kan(
        const float* __restrict__ x, const int* __restrict__ t_idx,
        const float* __restrict__ temb,
        const __hip_bfloat16* __restrict__ W,
        const float* __restrict__ bias,
        float* __restrict__ out)
{
    __shared__ char AsB[128 * 128];   // 128 rows x (64k * 2B) = 16 KB
    __shared__ char BsB[256 * 128];   // 256 cols x 128 B     = 32 KB
    const int t    = threadIdx.x;
    const int wave = t >> 6;
    const int lane = t & 63;
    const int m_base = blockIdx.x * 128;
    const int n_base = blockIdx.y * 256;
    const int wm = (wave >> 1) * 64;
    const int wn = (wave & 1) * 128;
    const int ll = lane & 15;
    const int q4 = lane >> 4;

    f32x4 acc[4][8] = {};

    // ---- B staging: thread t stages row lr, phys 16B slot s8, XOR swizzle ----
    const int lr = t >> 3;
    const int s8 = t & 7;
    const int cgB = s8 ^ (lr & 7);
    const __hip_bfloat16* bg = W + (long)(n_base + lr) * Ktot + cgB * 8;
    char* ldsB = BsB + wave * 1024;

    // ---- A generation: thread t handles i-chunk c (4 ch), rows rb+16j ----
    const int c  = t & 15;
    const int rb = t >> 4;

    // ---- fragment read offsets: phys chunk = (kk*4 + q4) ^ (ll&7) ----
    const int coff = (q4 ^ (ll & 7)) * 16;
    const int aoff = (wm + ll) * 128 + coff;
    const int boff = (wn + ll) * 128 + coff;

    for (int f6 = 0; f6 < 6; ++f6) {
        const float gv = -1.0f + 0.5f * (float)(f6 - 1);  // RBF center (f6>=1)
        #pragma unroll
        for (int half = 0; half < 2; ++half) {
            const int kt = (f6 * 2 + half) * 64;
            // stage B tile (async -> LDS); latency covered by A-gen VALU below
            #pragma unroll
            for (int q = 0; q < 8; ++q)
                GLDS16(bg + kt + (long)q * 32 * Ktot, ldsB + q * 4096);

            // generate A tile: 4 features per thread x 8 row-groups
            const int i = half * 64 + c * 4;
            float4 xv[8];
            #pragma unroll
            for (int j = 0; j < 8; ++j) {
                const int m = m_base + rb + j * 16;
                if (i < 120) {
                    xv[j] = *(const float4*)(x + (long)m * 120 + i);
                } else {
                    const int rt = t_idx[(m >> 9) % Hh];
                    xv[j] = *(const float4*)(temb + rt * 8 + (i - 120));
                }
            }
            #pragma unroll
            for (int j = 0; j < 8; ++j) {
                const int r = rb + j * 16;
                float fv[4];
                const float* vv = (const float*)&xv[j];
                #pragma unroll
                for (int e = 0; e < 4; ++e) {
                    const float v = vv[e];
                    if (f6 == 0) {
                        fv[e] = v * __builtin_amdgcn_rcpf(1.0f + __expf(-v));
                    } else {
                        const float d = v - gv;
                        fv[e] = __expf(-4.0f * d * d);
                    }
                }
                uint2 w;
                w.x = f2bf(fv[0]) | ((unsigned)f2bf(fv[1]) << 16);
                w.y = f2bf(fv[2]) | ((unsigned)f2bf(fv[3]) << 16);
                *(uint2*)(AsB + r * 128 + ((c >> 1) ^ (r & 7)) * 16 + (c & 1) * 8) = w;
            }
            __syncthreads();               // drains GLDS vmcnt + ds_write lgkm

            #pragma unroll
            for (int kk = 0; kk < 2; ++kk) {
                const int ao = kk ? (aoff ^ 64) : aoff;
                const int bo = kk ? (boff ^ 64) : boff;
                bf16x8 af[4], bf[8];
                #pragma unroll
                for (int mi = 0; mi < 4; ++mi) af[mi] = *(const bf16x8*)(AsB + ao + mi * 2048);
                #pragma unroll
                for (int ni = 0; ni < 8; ++ni) bf[ni] = *(const bf16x8*)(BsB + bo + ni * 2048);
                #pragma unroll
                for (int mi = 0; mi < 4; ++mi)
                    #pragma unroll
                    for (int ni = 0; ni < 8; ++ni)
                        acc[mi][ni] = __builtin_amdgcn_mfma_f32_16x16x32_bf16(
                            af[mi], bf[ni], acc[mi][ni], 0, 0, 0);
            }
            __syncthreads();               // LDS consumed before next stage
        }
    }

    // C/D layout: col = lane&15, row = (lane>>4)*4 + reg  [m89-verified]
    const int col0 = n_base + wn + ll;
    const int row0 = m_base + wm + q4 * 4;
    #pragma unroll
    for (int ni = 0; ni < 8; ++ni) {
        const int col = col0 + ni * 16;
        const float bv = bias[col];
        #pragma unroll
        for (int mi = 0; mi < 4; ++mi) {
            #pragma unroll
            for (int r = 0; r < 4; ++r) {
                out[(long)(row0 + mi * 16 + r) * Otot + col] = acc[mi][ni][r] + bv;
            }
        }
    }
}

extern "C" void kernel_launch(void* const* d_in, const int* in_sizes, int n_in,
                              void* d_out, int out_size, void* d_ws, size_t ws_size,
                              hipStream_t stream) {
    const float* x    = (const float*)d_in[0];
    const int*   tidx = (const int*)  d_in[1];
    const float* temb = (const float*)d_in[2];
    const float* bw   = (const float*)d_in[3];
    const float* bb   = (const float*)d_in[4];
    const float* sw   = (const float*)d_in[5];
    float* out = (float*)d_out;

    __hip_bfloat16* Wt = (__hip_bfloat16*)d_ws;   // 512*768*2 = 768 KiB

    prep_W<<<Otot * 192 / 256, 256, 0, stream>>>(bw, sw, (uint2*)Wt);
    gemm_kan<<<dim3(Mtot / 128, Otot / 256), 256, 0, stream>>>(
        x, tidx, temb, Wt, bb, out);
}

// Round 4
// 173.643 us; speedup vs baseline: 2.0000x; 2.0000x over previous
//
#include <hip/hip_runtime.h>
#include <hip/hip_bf16.h>

typedef __attribute__((ext_vector_type(4))) float f32x4;
typedef __attribute__((ext_vector_type(8))) short bf16x8;

// global -> LDS direct DMA, 16 B/lane. LDS dest = wave-uniform base + lane*16.
#define GLDS16(gp, lp) __builtin_amdgcn_global_load_lds( \
    (__attribute__((address_space(1))) void*)(void*)(gp), \
    (__attribute__((address_space(3))) void*)(lp), 16, 0, 0)

static constexpr int Mtot = 49152;   // 4*24*512 rows (b,h,n)
static constexpr int Otot = 512;
static constexpr int Hh   = 24;
// K order: k = i*6 + f (i: 0..119 = x-ch, 120..127 = t_emb; f: silu, rbf0..4)
// 8 K-iters of BK=96 (16 channels). LDS rows padded to 256B, chunk swizzle
// phys = ck ^ (row&7) baked into both A (ds_write) and B (prep_W image).

__device__ inline unsigned short f2bf(float f) {
    __hip_bfloat16 h = __float2bfloat16(f);
    unsigned short u;
    __builtin_memcpy(&u, &h, 2);
    return u;
}

// Wt image: [iter(8)][o(512)][16 chunks x 16B]; chunk p holds logical chunk
// ck = p ^ (o&7) (zeros if ck>=12). Logical: k_local = ck*8+e, k = iter*96+k_local.
__global__ __launch_bounds__(256) void prep_W(
        const float* __restrict__ bw, const float* __restrict__ sw,
        uint4* __restrict__ Wt)
{
    int tid = blockIdx.x * 256 + threadIdx.x;   // (iter*512 + o)*16 + p ; 65536 total
    int p    = tid & 15;
    int o    = (tid >> 4) & 511;
    int iter = tid >> 13;
    int ck = p ^ (o & 7);
    unsigned u[4] = {0u, 0u, 0u, 0u};
    if (ck < 12) {
        unsigned short s[8];
        #pragma unroll
        for (int e = 0; e < 8; ++e) {
            int k = iter * 96 + ck * 8 + e;
            int i = k / 6, f = k - i * 6;
            float v = (f == 0) ? bw[o * 128 + i] : sw[(o * 128 + i) * 5 + (f - 1)];
            s[e] = f2bf(v);
        }
        #pragma unroll
        for (int n = 0; n < 4; ++n) u[n] = s[2 * n] | ((unsigned)s[2 * n + 1] << 16);
    }
    Wt[tid] = make_uint4(u[0], u[1], u[2], u[3]);
}

// Fused KAN GEMM: block 128x128, 4 waves 2x2, wave 64x64, BK=96, 8 iters.
// A-tile generated in-kernel from x/temb (each x value read ONCE per block).
__global__ __launch_bounds__(256, 2) void gemm_kan(
        const float* __restrict__ x, const int* __restrict__ t_idx,
        const float* __restrict__ temb,
        const char* __restrict__ Wt,
        const float* __restrict__ bias,
        float* __restrict__ out)
{
    __shared__ char AsB[128 * 256];   // 32 KB, row-padded, swizzled
    __shared__ char BsB[128 * 256];   // 32 KB, GLDS verbatim image
    const int t    = threadIdx.x;
    const int wave = t >> 6;
    const int lane = t & 63;
    const int m_base = blockIdx.x * 128;
    const int n_base = blockIdx.y * 128;
    const int wm = (wave >> 1) * 64;
    const int wn = (wave & 1) * 64;
    const int ll = lane & 15;
    const int q4 = lane >> 4;

    f32x4 acc[4][4] = {};

    // ---- B staging: verbatim copy of the pre-swizzled Wt image ----
    const char* bsrc0 = Wt + (size_t)n_base * 256 + t * 16;
    char* ldsB = BsB + wave * 1024;   // wave-uniform; lane*16 added by HW

    // ---- A generation mapping: thread = (row, octet of 8 channels) ----
    const int row = t >> 1;
    const int oct = t & 1;
    const int ht  = t_idx[(m_base >> 9) % Hh];         // uniform per block
    const float* xrow = x + (size_t)(m_base + row) * 120;
    const float* trow = temb + ht * 8;

    float4 xa, xb;
    {   // prime iter 0
        const int i0 = 8 * oct;
        xa = *(const float4*)(xrow + i0);
        xb = *(const float4*)(xrow + i0 + 4);
    }

    for (int it = 0; it < 8; ++it) {
        // stage B tile (async); flies under the feature VALU below
        const char* bsrc = bsrc0 + (size_t)it * (512 * 256);
        #pragma unroll
        for (int q = 0; q < 8; ++q)
            GLDS16(bsrc + q * 4096, ldsB + q * 4096);

        // compute 8 channels x 6 features -> 48 bf16
        float v[8];
        v[0] = xa.x; v[1] = xa.y; v[2] = xa.z; v[3] = xa.w;
        v[4] = xb.x; v[5] = xb.y; v[6] = xb.z; v[7] = xb.w;

        // prefetch x for next iter (latency hidden under VALU+MFMA)
        if (it < 7) {
            const int i0 = (it + 1) * 16 + 8 * oct;
            const float* p = (i0 < 120) ? (xrow + i0) : (trow + (i0 - 120));
            xa = *(const float4*)p;
            xb = *(const float4*)(p + 4);
        }

        unsigned short s[48];
        #pragma unroll
        for (int c = 0; c < 8; ++c) {
            const float vv = v[c];
            s[c * 6 + 0] = f2bf(vv * __builtin_amdgcn_rcpf(1.0f + __expf(-vv)));
            #pragma unroll
            for (int g = 0; g < 5; ++g) {
                const float d = 2.0f * (vv - (-1.0f + 0.5f * g));
                s[c * 6 + 1 + g] = f2bf(__expf(-d * d));
            }
        }
        // write 6 swizzled 16B chunks: logical ck = 6*oct + j
        #pragma unroll
        for (int j = 0; j < 6; ++j) {
            const int ck = 6 * oct + j;
            const int phys = ck ^ (row & 7);
            unsigned u[4];
            #pragma unroll
            for (int n = 0; n < 4; ++n)
                u[n] = s[j * 8 + 2 * n] | ((unsigned)s[j * 8 + 2 * n + 1] << 16);
            *(uint4*)(AsB + row * 256 + phys * 16) = make_uint4(u[0], u[1], u[2], u[3]);
        }
        __syncthreads();               // drain GLDS B + ds_writes A

        #pragma unroll
        for (int kk = 0; kk < 3; ++kk) {
            bf16x8 af[4], bf[4];
            #pragma unroll
            for (int mi = 0; mi < 4; ++mi) {
                const int r = wm + mi * 16 + ll;
                af[mi] = *(const bf16x8*)(AsB + r * 256 + (((kk * 4 + q4) ^ (ll & 7)) * 16));
            }
            #pragma unroll
            for (int ni = 0; ni < 4; ++ni) {
                const int r = wn + ni * 16 + ll;
                bf[ni] = *(const bf16x8*)(BsB + r * 256 + (((kk * 4 + q4) ^ (ll & 7)) * 16));
            }
            #pragma unroll
            for (int mi = 0; mi < 4; ++mi)
                #pragma unroll
                for (int ni = 0; ni < 4; ++ni)
                    acc[mi][ni] = __builtin_amdgcn_mfma_f32_16x16x32_bf16(
                        af[mi], bf[ni], acc[mi][ni], 0, 0, 0);
        }
        __syncthreads();               // LDS consumed before next stage
    }

    // C/D layout: col = lane&15, row = (lane>>4)*4 + reg  [m89-verified]
    const int col0 = n_base + wn + ll;
    const int row0 = m_base + wm + q4 * 4;
    #pragma unroll
    for (int ni = 0; ni < 4; ++ni) {
        const int col = col0 + ni * 16;
        const float bv = bias[col];
        #pragma unroll
        for (int mi = 0; mi < 4; ++mi) {
            #pragma unroll
            for (int r = 0; r < 4; ++r) {
                out[(long)(row0 + mi * 16 + r) * Otot + col] = acc[mi][ni][r] + bv;
            }
        }
    }
}

extern "C" void kernel_launch(void* const* d_in, const int* in_sizes, int n_in,
                              void* d_out, int out_size, void* d_ws, size_t ws_size,
                              hipStream_t stream) {
    const float* x    = (const float*)d_in[0];
    const int*   tidx = (const int*)  d_in[1];
    const float* temb = (const float*)d_in[2];
    const float* bw   = (const float*)d_in[3];
    const float* bb   = (const float*)d_in[4];
    const float* sw   = (const float*)d_in[5];
    float* out = (float*)d_out;

    char* Wt = (char*)d_ws;   // 8*512*256 B = 1 MiB swizzled image

    prep_W<<<65536 / 256, 256, 0, stream>>>(bw, sw, (uint4*)Wt);
    gemm_kan<<<dim3(Mtot / 128, Otot / 128), 256, 0, stream>>>(
        x, tidx, temb, Wt, bb, out);
}